// Round 6
// baseline (245.253 us; speedup 1.0000x reference)
//
#include <hip/hip_runtime.h>

// Sizes fixed by the problem.
#define BS    64
#define KDIM  256   // in_dim
#define ICAP  256   // I = 16*16
#define JCAP  64    // J out-caps
#define D2    32
#define OUTD  2048  // J*D2

typedef short bf16x8 __attribute__((ext_vector_type(8)));
typedef float f32x4  __attribute__((ext_vector_type(4)));

static __device__ __forceinline__ float bf2f(unsigned u16) {
  union { unsigned u; float f; } v; v.u = u16 << 16; return v.f;
}
static __device__ __forceinline__ unsigned short f2bf(float x) {
  union { float f; unsigned u; } v; v.f = x;
  unsigned r = v.u + 0x7fffu + ((v.u >> 16) & 1u);
  return (unsigned short)(r >> 16);
}

// group barrier: 4 blocks of one b; one counter per event (memset-zeroed).
static __device__ __forceinline__ void group_barrier(int* c) {
  __syncthreads();
  if (threadIdx.x == 0) {
    __hip_atomic_fetch_add(c, 1, __ATOMIC_ACQ_REL, __HIP_MEMORY_SCOPE_AGENT);
    while (__hip_atomic_load(c, __ATOMIC_ACQUIRE, __HIP_MEMORY_SCOPE_AGENT) < 4)
      __builtin_amdgcn_s_sleep(2);
  }
  __syncthreads();
}
// chip barrier: all 256 blocks, used exactly once (after prep).
static __device__ __forceinline__ void chip_barrier(int* c) {
  __syncthreads();
  if (threadIdx.x == 0) {
    __hip_atomic_fetch_add(c, 1, __ATOMIC_ACQ_REL, __HIP_MEMORY_SCOPE_AGENT);
    while (__hip_atomic_load(c, __ATOMIC_ACQUIRE, __HIP_MEMORY_SCOPE_AGENT) < 256)
      __builtin_amdgcn_s_sleep(4);
  }
  __syncthreads();
}

// ---------------------------------------------------------------------------
// mega: 256 blocks = (b = bid&63, q = bid>>6), 1024 threads (16 waves).
//  P1 (q=k-quarter): x f32 -> xKI bf16 + xT bf16; + W -> Wbfh/Wbfl (8 rows/blk)
//  P2 (q=i-quarter): c0 softmax -> cm bf16 + cpart + btr (transposed logits).
//  [chip barrier]
//  pass 1..3:
//   A (q=j-quarter): Y MFMA -> ybf hi/lo LDS; S-MFMA diagonal (Wbf x ybf,
//     3 cross terms) -> s; squash -> v (pass3: out, return); U = v.Wbf hi+lo.
//   [group bar]  B (q=i-quarter): db MFMA (hi+lo); logits in regs; softmax.
//   [group bar]
// ---------------------------------------------------------------------------
__global__ __launch_bounds__(1024) void mega(
    const float* __restrict__ x,            // [BS][KDIM][ICAP] f32
    const float* __restrict__ Binit,        // [BS][JCAP][ICAP] f32
    const float* __restrict__ W,            // [OUTD][KDIM] f32
    const float* __restrict__ Wb,           // [OUTD] f32
    unsigned short* __restrict__ xT,        // [BS][ICAP][KDIM] bf16
    unsigned short* __restrict__ xKI,       // [BS][KDIM][ICAP] bf16
    unsigned short* __restrict__ Wbfh,      // [OUTD][KDIM] bf16
    unsigned short* __restrict__ Wbfl,      // [OUTD][KDIM] bf16
    unsigned short* __restrict__ cm,        // [BS][JCAP][ICAP] bf16
    unsigned short* __restrict__ Uhi,       // [BS][JCAP][KDIM] bf16
    unsigned short* __restrict__ Ulo,       // [BS][JCAP][KDIM] bf16
    float* __restrict__ btr,                // [BS][ICAP][JCAP] f32
    float* __restrict__ cpart,              // [BS][4][JCAP] f32
    float* __restrict__ ubg,                // [BS][JCAP] f32
    int* __restrict__ cnt,                  // [BS*16 + 16] counters
    float* __restrict__ outp)               // [BS][OUTD] f32
{
  __shared__ union {
    float xs[64][260];                                           // P1
    struct { float Bs[64][68]; float mx[64]; float inv[64]; } p2;
    struct {
      unsigned short ybf[2][16][264];      // Y hi/lo bf16 [j-local][k]
      float sv[16][33];
      float vls[16][33];
    } a;
    float dbl[64][65];                                           // phase B
  } sm;

  const int t   = threadIdx.x;        // 0..1023
  const int u   = blockIdx.x;         // 0..255
  const int b   = u & 63;
  const int q   = u >> 6;
  const int w   = t >> 6;             // wave 0..15
  const int l   = t & 63;
  const int l15 = l & 15;
  const int lhi = (l >> 4) & 3;
  int* gcnt = cnt + b * 16;

  // ---------------- P1: x prep (q = k-quarter) + W cast ----------------
  {
    const int k0  = q * 64;
    const int r   = t >> 4;             // k-row 0..63
    const int c16 = (t & 15) * 16;      // i-chunk
    const float* src = x + ((size_t)(b * KDIM + k0 + r)) * ICAP + c16;
    f32x4 vv[4];
#pragma unroll
    for (int e = 0; e < 4; ++e) vv[e] = *(const f32x4*)(src + e * 4);
    {   // xKI straight cast
      const float* fv = (const float*)vv;
      unsigned pk[8];
#pragma unroll
      for (int h = 0; h < 8; ++h)
        pk[h] = (unsigned)f2bf(fv[2 * h]) | ((unsigned)f2bf(fv[2 * h + 1]) << 16);
      unsigned short* dst = xKI + ((size_t)(b * KDIM + k0 + r)) * ICAP + c16;
      *(uint4*)(dst)     = *(uint4*)&pk[0];
      *(uint4*)(dst + 8) = *(uint4*)&pk[4];
    }
#pragma unroll
    for (int e = 0; e < 4; ++e) *(f32x4*)&sm.xs[r][c16 + e * 4] = vv[e];
  }
  {   // W cast: block u covers rows [u*8, u*8+8)
    const int row = u * 8 + (t >> 7);
    const int col = (t & 127) * 2;
    const float* wsrc = W + (size_t)row * KDIM + col;
    float a0 = wsrc[0], a1 = wsrc[1];
    unsigned short h0 = f2bf(a0), h1 = f2bf(a1);
    unsigned hi = (unsigned)h0 | ((unsigned)h1 << 16);
    unsigned lo = (unsigned)f2bf(a0 - bf2f(h0)) |
                  ((unsigned)f2bf(a1 - bf2f(h1)) << 16);
    *(unsigned*)(Wbfh + (size_t)row * KDIM + col) = hi;
    *(unsigned*)(Wbfl + (size_t)row * KDIM + col) = lo;
  }
  __syncthreads();
  {   // xT transpose out of LDS
    const int k0 = q * 64;
    const int i  = t >> 2;              // 0..255
    const int kq = (t & 3) * 16;
    unsigned pk[8];
#pragma unroll
    for (int h = 0; h < 8; ++h)
      pk[h] = (unsigned)f2bf(sm.xs[kq + 2 * h][i]) |
              ((unsigned)f2bf(sm.xs[kq + 2 * h + 1][i]) << 16);
    unsigned short* dst = xT + ((size_t)(b * ICAP + i)) * KDIM + k0 + kq;
    *(uint4*)(dst)     = *(uint4*)&pk[0];
    *(uint4*)(dst + 8) = *(uint4*)&pk[4];
  }
  __syncthreads();

  // ---------------- P2: Binit softmax (q = i-quarter) ----------------
  {
    const int i0 = q * 64;
    {
      const int j = t >> 4, c4 = (t & 15) * 4;
      *(f32x4*)&sm.p2.Bs[j][c4] =
          *(const f32x4*)(Binit + ((size_t)(b * JCAP + j)) * ICAP + i0 + c4);
    }
    __syncthreads();
    if (t < 64) {
      float m = -3.0e38f;
      for (int j = 0; j < 64; ++j) m = fmaxf(m, sm.p2.Bs[j][t]);
      float se = 0.f;
      for (int j = 0; j < 64; ++j) se += __expf(sm.p2.Bs[j][t] - m);
      sm.p2.mx[t] = m; sm.p2.inv[t] = 1.0f / se;
    }
    __syncthreads();
    {   // cm + cpart
      const int j = t >> 4, i4 = (t & 15) * 4;
      float cv[4];
#pragma unroll
      for (int e = 0; e < 4; ++e)
        cv[e] = __expf(sm.p2.Bs[j][i4 + e] - sm.p2.mx[i4 + e]) * sm.p2.inv[i4 + e];
      unsigned pk[2];
      pk[0] = (unsigned)f2bf(cv[0]) | ((unsigned)f2bf(cv[1]) << 16);
      pk[1] = (unsigned)f2bf(cv[2]) | ((unsigned)f2bf(cv[3]) << 16);
      *(uint2*)(cm + ((size_t)(b * JCAP + j)) * ICAP + i0 + i4) = *(uint2*)pk;
      float cs = cv[0] + cv[1] + cv[2] + cv[3];
      cs += __shfl_xor(cs, 1, 64);
      cs += __shfl_xor(cs, 2, 64);
      cs += __shfl_xor(cs, 4, 64);
      cs += __shfl_xor(cs, 8, 64);
      if ((t & 15) == 0) cpart[((size_t)(b * 4 + q)) * JCAP + j] = cs;
    }
    {   // btr: transposed logits for pass-1 coalesced read
      const int il = t >> 4, j4 = (t & 15) * 4;
      f32x4 o;
      o.x = sm.p2.Bs[j4 + 0][il]; o.y = sm.p2.Bs[j4 + 1][il];
      o.z = sm.p2.Bs[j4 + 2][il]; o.w = sm.p2.Bs[j4 + 3][il];
      *(f32x4*)(btr + ((size_t)(b * ICAP + i0 + il)) * JCAP + j4) = o;
    }
  }
  chip_barrier(cnt + BS * 16);   // covers xT/xKI/cm/cpart/btr + W cast

  // ---------------- routing passes ----------------
  float blogreg[4];

  for (int pass = 1; pass <= 3; ++pass) {
    // ======== phase A (q = j-quarter) ========
    {   // Y MFMA -> ybf hi/lo: yt[jl][k] = sum_i xKI[k][i]*cm[q*16+jl][i]
      f32x4 acc = (f32x4){0.f, 0.f, 0.f, 0.f};
      const unsigned short* Ar =
          xKI + ((size_t)(b * KDIM + w * 16 + l15)) * ICAP + lhi * 8;
      const unsigned short* Br =
          cm + ((size_t)(b * JCAP + q * 16 + l15)) * ICAP + lhi * 8;
#pragma unroll
      for (int kk = 0; kk < 8; ++kk) {
        bf16x8 a  = *(const bf16x8*)(Ar + kk * 32);
        bf16x8 bb = *(const bf16x8*)(Br + kk * 32);
        acc = __builtin_amdgcn_mfma_f32_16x16x32_bf16(a, bb, acc, 0, 0, 0);
      }
      // D: col(l15) = j-local, row(lhi*4+r) = k-local -> 4 consecutive k
      unsigned hpk[2], lpk[2];
#pragma unroll
      for (int h = 0; h < 2; ++h) {
        unsigned short y0 = f2bf(acc[2 * h]), y1 = f2bf(acc[2 * h + 1]);
        hpk[h] = (unsigned)y0 | ((unsigned)y1 << 16);
        lpk[h] = (unsigned)f2bf(acc[2 * h] - bf2f(y0)) |
                 ((unsigned)f2bf(acc[2 * h + 1] - bf2f(y1)) << 16);
      }
      const int kc = w * 16 + lhi * 4;
      *(uint2*)&sm.a.ybf[0][l15][kc] = *(uint2*)hpk;
      *(uint2*)&sm.a.ybf[1][l15][kc] = *(uint2*)lpk;
    }
    __syncthreads();

    // S-MFMA: wave w computes s[jg][0..31], jg = q*16 + w (diagonal extract)
    {
      const int jg = q * 16 + w;
      f32x4 accA = (f32x4){0.f, 0.f, 0.f, 0.f};   // m-tile 2w   (d 0..15)
      f32x4 accB = (f32x4){0.f, 0.f, 0.f, 0.f};   // m-tile 2w+1 (d 16..31)
      const size_t wrow = (size_t)(q * 512 + w * 32 + l15) * KDIM + lhi * 8;
      const unsigned short* WhP = Wbfh + wrow;
      const unsigned short* WlP = Wbfl + wrow;
#pragma unroll
      for (int kk = 0; kk < 8; ++kk) {
        bf16x8 yh = *(const bf16x8*)&sm.a.ybf[0][l15][lhi * 8 + kk * 32];
        bf16x8 yl = *(const bf16x8*)&sm.a.ybf[1][l15][lhi * 8 + kk * 32];
        bf16x8 wh0 = *(const bf16x8*)(WhP + kk * 32);
        bf16x8 wl0 = *(const bf16x8*)(WlP + kk * 32);
        bf16x8 wh1 = *(const bf16x8*)(WhP + (size_t)16 * KDIM + kk * 32);
        bf16x8 wl1 = *(const bf16x8*)(WlP + (size_t)16 * KDIM + kk * 32);
        accA = __builtin_amdgcn_mfma_f32_16x16x32_bf16(wh0, yh, accA, 0, 0, 0);
        accA = __builtin_amdgcn_mfma_f32_16x16x32_bf16(wh0, yl, accA, 0, 0, 0);
        accA = __builtin_amdgcn_mfma_f32_16x16x32_bf16(wl0, yh, accA, 0, 0, 0);
        accB = __builtin_amdgcn_mfma_f32_16x16x32_bf16(wh1, yh, accB, 0, 0, 0);
        accB = __builtin_amdgcn_mfma_f32_16x16x32_bf16(wh1, yl, accB, 0, 0, 0);
        accB = __builtin_amdgcn_mfma_f32_16x16x32_bf16(wl1, yh, accB, 0, 0, 0);
      }
      // diagonal: need col (l&15) == j-local == w; rows (l>>4)*4+r = d-local
      if ((l & 15) == w) {
        *(f32x4*)&sm.a.sv[w][(l >> 4) * 4]      = accA;
        *(f32x4*)&sm.a.sv[w][16 + (l >> 4) * 4] = accB;
      }
      // squash for jg (wave-local; ds ordering within wave)
      const int jd0 = jg * 32;
      float svv = sm.a.sv[w][l & 31];
      const float cs = cpart[((size_t)(b * 4 + 0)) * JCAP + jg] +
                       cpart[((size_t)(b * 4 + 1)) * JCAP + jg] +
                       cpart[((size_t)(b * 4 + 2)) * JCAP + jg] +
                       cpart[((size_t)(b * 4 + 3)) * JCAP + jg];
      const float wbv = Wb[jd0 + (l & 31)];
      svv += cs * wbv;
      float sq = svv * svv;
      sq += __shfl_xor(sq, 1, 64);
      sq += __shfl_xor(sq, 2, 64);
      sq += __shfl_xor(sq, 4, 64);
      sq += __shfl_xor(sq, 8, 64);
      sq += __shfl_xor(sq, 16, 64);
      const float scale = (sq / (1.0f + sq)) / sqrtf(sq + 1e-8f);
      const float v = scale * svv;
      if (pass == 3) {
        if (l < 32) outp[(size_t)b * OUTD + jd0 + l] = v;
      } else {
        if (l < 32) sm.a.vls[w][l] = v;
        float up = v * wbv;
        up += __shfl_xor(up, 1, 64);
        up += __shfl_xor(up, 2, 64);
        up += __shfl_xor(up, 4, 64);
        up += __shfl_xor(up, 8, 64);
        up += __shfl_xor(up, 16, 64);
        if (l == 0) ubg[(size_t)b * JCAP + jg] = up;
      }
    }
    if (pass == 3) return;

    // U-phase: wave w owns jg; lanes span k; W = hi+lo bf16 (f32 W stays cold)
    {
      const int jg = q * 16 + w;
      f32x4 acc = (f32x4){0.f, 0.f, 0.f, 0.f};
      const size_t base = (size_t)(jg * 32) * KDIM + l * 4;
#pragma unroll 4
      for (int d = 0; d < 32; ++d) {
        const float vd = sm.a.vls[w][d];
        uint2 uh = *(const uint2*)(Wbfh + base + (size_t)d * KDIM);
        uint2 ul = *(const uint2*)(Wbfl + base + (size_t)d * KDIM);
        float w0 = bf2f(uh.x & 0xffffu) + bf2f(ul.x & 0xffffu);
        float w1 = bf2f(uh.x >> 16)     + bf2f(ul.x >> 16);
        float w2 = bf2f(uh.y & 0xffffu) + bf2f(ul.y & 0xffffu);
        float w3 = bf2f(uh.y >> 16)     + bf2f(ul.y >> 16);
        acc.x += vd * w0; acc.y += vd * w1;
        acc.z += vd * w2; acc.w += vd * w3;
      }
      unsigned short h0 = f2bf(acc.x), h1 = f2bf(acc.y);
      unsigned short h2 = f2bf(acc.z), h3 = f2bf(acc.w);
      unsigned ph[2], pl[2];
      ph[0] = (unsigned)h0 | ((unsigned)h1 << 16);
      ph[1] = (unsigned)h2 | ((unsigned)h3 << 16);
      pl[0] = (unsigned)f2bf(acc.x - bf2f(h0)) | ((unsigned)f2bf(acc.y - bf2f(h1)) << 16);
      pl[1] = (unsigned)f2bf(acc.z - bf2f(h2)) | ((unsigned)f2bf(acc.w - bf2f(h3)) << 16);
      size_t off = ((size_t)(b * JCAP + jg)) * KDIM + l * 4;
      *(uint2*)(Uhi + off) = *(uint2*)ph;
      *(uint2*)(Ulo + off) = *(uint2*)pl;
    }
    group_barrier(gcnt + 2 * (pass - 1));

    // ======== phase B: db + softmax (q = i-quarter) ========
    {
      const int i0b = q * 64;
      const int mt  = w & 3, nj = w >> 2;
      f32x4 acc = (f32x4){0.f, 0.f, 0.f, 0.f};
      const unsigned short* Ar =
          xT + ((size_t)(b * ICAP + i0b + mt * 16 + l15)) * KDIM + lhi * 8;
      const unsigned short* Bh =
          Uhi + ((size_t)(b * JCAP + nj * 16 + l15)) * KDIM + lhi * 8;
      const unsigned short* Bl =
          Ulo + ((size_t)(b * JCAP + nj * 16 + l15)) * KDIM + lhi * 8;
#pragma unroll
      for (int kk = 0; kk < 8; ++kk) {
        bf16x8 a  = *(const bf16x8*)(Ar + kk * 32);
        bf16x8 bh = *(const bf16x8*)(Bh + kk * 32);
        acc = __builtin_amdgcn_mfma_f32_16x16x32_bf16(a, bh, acc, 0, 0, 0);
        bf16x8 bl = *(const bf16x8*)(Bl + kk * 32);
        acc = __builtin_amdgcn_mfma_f32_16x16x32_bf16(a, bl, acc, 0, 0, 0);
      }
#pragma unroll
      for (int r = 0; r < 4; ++r)
        sm.dbl[mt * 16 + lhi * 4 + r][nj * 16 + l15] = acc[r];
    }
    __syncthreads();
    {   // softmax over j; logits live in regs (blogreg[4])
      const int i0b = q * 64;
      const int il = t >> 4, jc = (t & 15) * 4;
      f32x4 ub4 = *(const f32x4*)(ubg + (size_t)b * JCAP + jc);
      float bn[4];
      if (pass == 1) {
        f32x4 bo = *(const f32x4*)(btr + ((size_t)(b * ICAP + i0b + il)) * JCAP + jc);
        bn[0] = bo.x; bn[1] = bo.y; bn[2] = bo.z; bn[3] = bo.w;
      } else {
#pragma unroll
        for (int e = 0; e < 4; ++e) bn[e] = blogreg[e];
      }
      const float ubv[4] = {ub4.x, ub4.y, ub4.z, ub4.w};
#pragma unroll
      for (int e = 0; e < 4; ++e) {
        bn[e] += sm.dbl[il][jc + e] + ubv[e];
        blogreg[e] = bn[e];
      }
      float mx = fmaxf(fmaxf(bn[0], bn[1]), fmaxf(bn[2], bn[3]));
      mx = fmaxf(mx, __shfl_xor(mx, 1, 64));
      mx = fmaxf(mx, __shfl_xor(mx, 2, 64));
      mx = fmaxf(mx, __shfl_xor(mx, 4, 64));
      mx = fmaxf(mx, __shfl_xor(mx, 8, 64));
      float e4[4], se = 0.f;
#pragma unroll
      for (int e = 0; e < 4; ++e) { e4[e] = __expf(bn[e] - mx); se += e4[e]; }
      se += __shfl_xor(se, 1, 64);
      se += __shfl_xor(se, 2, 64);
      se += __shfl_xor(se, 4, 64);
      se += __shfl_xor(se, 8, 64);
      const float inv = 1.0f / se;
      f32x4 cw; cw.x = e4[0] * inv; cw.y = e4[1] * inv;
      cw.z = e4[2] * inv; cw.w = e4[3] * inv;
      *(f32x4*)&sm.dbl[il][jc] = cw;
    }
    __syncthreads();
    {   // transpose-pack c -> cm + cpart
      const int i0b = q * 64;
      const int j2 = t >> 4, ic4 = (t & 15) * 4;
      float c0 = sm.dbl[ic4 + 0][j2], c1 = sm.dbl[ic4 + 1][j2];
      float c2 = sm.dbl[ic4 + 2][j2], c3 = sm.dbl[ic4 + 3][j2];
      unsigned pk[2];
      pk[0] = (unsigned)f2bf(c0) | ((unsigned)f2bf(c1) << 16);
      pk[1] = (unsigned)f2bf(c2) | ((unsigned)f2bf(c3) << 16);
      *(uint2*)(cm + ((size_t)(b * JCAP + j2)) * ICAP + i0b + ic4) = *(uint2*)pk;
      float cs = c0 + c1 + c2 + c3;
      cs += __shfl_xor(cs, 1, 64);
      cs += __shfl_xor(cs, 2, 64);
      cs += __shfl_xor(cs, 4, 64);
      cs += __shfl_xor(cs, 8, 64);
      if ((t & 15) == 0) cpart[((size_t)(b * 4 + q)) * JCAP + j2] = cs;
    }
    group_barrier(gcnt + 2 * (pass - 1) + 1);
  }
}

// ---------------------------------------------------------------------------
extern "C" void kernel_launch(void* const* d_in, const int* in_sizes, int n_in,
                              void* d_out, int out_size, void* d_ws, size_t ws_size,
                              hipStream_t stream) {
  const float* x  = (const float*)d_in[0];
  const float* bi = (const float*)d_in[1];
  const float* W  = (const float*)d_in[2];
  const float* Wb = (const float*)d_in[3];
  float* out = (float*)d_out;

  char* ws = (char*)d_ws;
  const size_t MiB = 1024 * 1024;
  unsigned short* xT   = (unsigned short*)(ws + 0 * MiB);    // 8 MiB
  unsigned short* xKI  = (unsigned short*)(ws + 8 * MiB);    // 8 MiB
  unsigned short* cm   = (unsigned short*)(ws + 16 * MiB);   // 2 MiB
  unsigned short* Uhi  = (unsigned short*)(ws + 18 * MiB);   // 2 MiB
  unsigned short* Ulo  = (unsigned short*)(ws + 20 * MiB);   // 2 MiB
  float* btr           = (float*)(ws + 22 * MiB);            // 4 MiB
  float* cpart         = (float*)(ws + 26 * MiB);            // 64 KiB
  float* ubg           = (float*)(ws + 27 * MiB);            // 16 KiB
  int*   cnt           = (int*)(ws + 28 * MiB);              // 8 KiB
  unsigned short* Wbfh = (unsigned short*)(ws + 29 * MiB);   // 1 MiB
  unsigned short* Wbfl = (unsigned short*)(ws + 30 * MiB);   // 1 MiB

  hipMemsetAsync(cnt, 0, (BS * 16 + 16) * sizeof(int), stream);
  mega<<<dim3(256), dim3(1024), 0, stream>>>(x, bi, W, Wb, xT, xKI, Wbfh, Wbfl,
                                             cm, Uhi, Ulo, btr, cpart, ubg,
                                             cnt, out);
}

// Round 7
// 220.712 us; speedup vs baseline: 1.1112x; 1.1112x over previous
//
#include <hip/hip_runtime.h>

// Sizes fixed by the problem.
#define BS    64
#define KDIM  256   // in_dim
#define ICAP  256   // I = 16*16
#define JCAP  64    // J out-caps
#define D2    32
#define OUTD  2048  // J*D2

typedef short bf16x8 __attribute__((ext_vector_type(8)));
typedef float f32x4  __attribute__((ext_vector_type(4)));

static __device__ __forceinline__ float bf2f(unsigned u16) {
  union { unsigned u; float f; } v; v.u = u16 << 16; return v.f;
}
static __device__ __forceinline__ unsigned short f2bf(float x) {
  union { float f; unsigned u; } v; v.f = x;
  unsigned r = v.u + 0x7fffu + ((v.u >> 16) & 1u);
  return (unsigned short)(r >> 16);
}

// group barrier: the 4 blocks of one b; one counter per event (memset-zeroed).
static __device__ __forceinline__ void group_barrier(int* c) {
  __syncthreads();
  if (threadIdx.x == 0) {
    __hip_atomic_fetch_add(c, 1, __ATOMIC_ACQ_REL, __HIP_MEMORY_SCOPE_AGENT);
    while (__hip_atomic_load(c, __ATOMIC_ACQUIRE, __HIP_MEMORY_SCOPE_AGENT) < 4)
      __builtin_amdgcn_s_sleep(2);
  }
  __syncthreads();
}

// ---------------------------------------------------------------------------
// mega: 256 blocks = (b = bid&63, q = bid>>6), 1024 threads (16 waves).
//  P1 (q=k-quarter): x f32 -> xKI bf16 + xT bf16.
//  P2 (q=i-quarter): c0 softmax -> cm bf16 + cpart + btr.
//  [bar]
//  pass 1..2:
//   A (q=j-quarter): prefetch xT frags -> regs; Y MFMA -> yt LDS;
//     s scatter-stream (wave=j, lane=(d,khalf)) + squash -> v,ub;
//     U = v.W -> LDS bf16 hi/lo; db MFMA (xT regs x U LDS) -> dbg global.
//   [bar]
//   B (q=i-quarter): softmax(btr/regs + dbg + ub) -> cm + cpart.  [bar]
//  pass 3: Y; s -> squash -> out.
// ---------------------------------------------------------------------------
__global__ __launch_bounds__(1024) void mega(
    const float* __restrict__ x,            // [BS][KDIM][ICAP] f32
    const float* __restrict__ Binit,        // [BS][JCAP][ICAP] f32
    const float* __restrict__ W,            // [OUTD][KDIM] f32
    const float* __restrict__ Wb,           // [OUTD] f32
    unsigned short* __restrict__ xT,        // [BS][ICAP][KDIM] bf16
    unsigned short* __restrict__ xKI,       // [BS][KDIM][ICAP] bf16
    unsigned short* __restrict__ cm,        // [BS][JCAP][ICAP] bf16
    float* __restrict__ dbg,                // [BS][4][ICAP][16] f32
    float* __restrict__ btr,                // [BS][ICAP][JCAP] f32
    float* __restrict__ cpart,              // [BS][4][JCAP] f32
    float* __restrict__ ubg,                // [BS][JCAP] f32
    int* __restrict__ cnt,                  // [BS][8] barrier counters
    float* __restrict__ outp)               // [BS][OUTD] f32
{
  __shared__ union {
    float xs[64][260];                                           // P1
    struct { float Bs[64][68]; float mx[64]; float inv[64]; } p2;
    struct {
      float yt[16][260];                   // Y^T [j-local][k] f32
      float vls[16][33];                   // v   [j-local][d]
      unsigned short ubf[2][16][264];      // U hi/lo bf16 [j-local][k]
    } a;
    float dbl[64][65];                                           // B softmax
  } sm;

  const int t   = threadIdx.x;        // 0..1023
  const int u   = blockIdx.x;         // 0..255
  const int b   = u & 63;
  const int q   = u >> 6;
  const int w   = t >> 6;             // wave 0..15
  const int l   = t & 63;
  const int l15 = l & 15;
  const int lhi = l >> 4;             // 0..3
  int* gcnt = cnt + b * 8;

  // ---------------- P1: x prep (q = k-quarter) ----------------
  {
    const int k0  = q * 64;
    const int r   = t >> 4;             // k-row 0..63
    const int c16 = (t & 15) * 16;      // i-chunk
    const float* src = x + ((size_t)(b * KDIM + k0 + r)) * ICAP + c16;
    f32x4 vv[4];
#pragma unroll
    for (int e = 0; e < 4; ++e) vv[e] = *(const f32x4*)(src + e * 4);
    {   // xKI straight cast
      const float* fv = (const float*)vv;
      unsigned pk[8];
#pragma unroll
      for (int h = 0; h < 8; ++h)
        pk[h] = (unsigned)f2bf(fv[2 * h]) | ((unsigned)f2bf(fv[2 * h + 1]) << 16);
      unsigned short* dst = xKI + ((size_t)(b * KDIM + k0 + r)) * ICAP + c16;
      *(uint4*)(dst)     = *(uint4*)&pk[0];
      *(uint4*)(dst + 8) = *(uint4*)&pk[4];
    }
#pragma unroll
    for (int e = 0; e < 4; ++e) *(f32x4*)&sm.xs[r][c16 + e * 4] = vv[e];
  }
  __syncthreads();
  {   // xT transpose out of LDS
    const int k0 = q * 64;
    const int i  = t >> 2;              // 0..255
    const int kq = (t & 3) * 16;
    unsigned pk[8];
#pragma unroll
    for (int h = 0; h < 8; ++h)
      pk[h] = (unsigned)f2bf(sm.xs[kq + 2 * h][i]) |
              ((unsigned)f2bf(sm.xs[kq + 2 * h + 1][i]) << 16);
    unsigned short* dst = xT + ((size_t)(b * ICAP + i)) * KDIM + k0 + kq;
    *(uint4*)(dst)     = *(uint4*)&pk[0];
    *(uint4*)(dst + 8) = *(uint4*)&pk[4];
  }
  __syncthreads();

  // ---------------- P2: Binit softmax (q = i-quarter) ----------------
  {
    const int i0 = q * 64;
    {
      const int j = t >> 4, c4 = (t & 15) * 4;
      *(f32x4*)&sm.p2.Bs[j][c4] =
          *(const f32x4*)(Binit + ((size_t)(b * JCAP + j)) * ICAP + i0 + c4);
    }
    __syncthreads();
    if (t < 64) {
      float m = -3.0e38f;
      for (int j = 0; j < 64; ++j) m = fmaxf(m, sm.p2.Bs[j][t]);
      float se = 0.f;
      for (int j = 0; j < 64; ++j) se += __expf(sm.p2.Bs[j][t] - m);
      sm.p2.mx[t] = m; sm.p2.inv[t] = 1.0f / se;
    }
    __syncthreads();
    {   // cm + cpart
      const int j = t >> 4, i4 = (t & 15) * 4;
      float cv[4];
#pragma unroll
      for (int e = 0; e < 4; ++e)
        cv[e] = __expf(sm.p2.Bs[j][i4 + e] - sm.p2.mx[i4 + e]) * sm.p2.inv[i4 + e];
      unsigned pk[2];
      pk[0] = (unsigned)f2bf(cv[0]) | ((unsigned)f2bf(cv[1]) << 16);
      pk[1] = (unsigned)f2bf(cv[2]) | ((unsigned)f2bf(cv[3]) << 16);
      *(uint2*)(cm + ((size_t)(b * JCAP + j)) * ICAP + i0 + i4) = *(uint2*)pk;
      float cs = cv[0] + cv[1] + cv[2] + cv[3];
      cs += __shfl_xor(cs, 1, 64);
      cs += __shfl_xor(cs, 2, 64);
      cs += __shfl_xor(cs, 4, 64);
      cs += __shfl_xor(cs, 8, 64);
      if ((t & 15) == 0) cpart[((size_t)(b * 4 + q)) * JCAP + j] = cs;
    }
    {   // btr: transposed logits for pass-1 coalesced read
      const int il = t >> 4, j4 = (t & 15) * 4;
      f32x4 o;
      o.x = sm.p2.Bs[j4 + 0][il]; o.y = sm.p2.Bs[j4 + 1][il];
      o.z = sm.p2.Bs[j4 + 2][il]; o.w = sm.p2.Bs[j4 + 3][il];
      *(f32x4*)(btr + ((size_t)(b * ICAP + i0 + il)) * JCAP + j4) = o;
    }
  }
  group_barrier(gcnt + 0);

  // ---------------- routing passes ----------------
  float blogreg[4];

  for (int pass = 1; pass <= 3; ++pass) {
    // ---- prefetch xT A-fragments for db (pass-invariant addresses) ----
    bf16x8 xtf[8];
    if (pass != 3) {
      const unsigned short* Ar =
          xT + ((size_t)(b * ICAP + w * 16 + l15)) * KDIM + lhi * 8;
#pragma unroll
      for (int kk = 0; kk < 8; ++kk) xtf[kk] = *(const bf16x8*)(Ar + kk * 32);
    }

    // ---- Y MFMA: yt[j-local][k] = sum_i xKI[k][i]*cm[q*16+jl][i] ----
    {
      f32x4 acc = (f32x4){0.f, 0.f, 0.f, 0.f};
      const unsigned short* Ar =
          xKI + ((size_t)(b * KDIM + w * 16 + l15)) * ICAP + lhi * 8;
      const unsigned short* Br =
          cm + ((size_t)(b * JCAP + q * 16 + l15)) * ICAP + lhi * 8;
#pragma unroll
      for (int kk = 0; kk < 8; ++kk) {
        bf16x8 a  = *(const bf16x8*)(Ar + kk * 32);
        bf16x8 bb = *(const bf16x8*)(Br + kk * 32);
        acc = __builtin_amdgcn_mfma_f32_16x16x32_bf16(a, bb, acc, 0, 0, 0);
      }
      *(f32x4*)&sm.a.yt[l15][w * 16 + lhi * 4] = acc;
    }
    __syncthreads();

    // ---- s: wave w owns j = q*16+w; lane = (d = l>>1, khalf = l&1) ----
    {
      const int jg = q * 16 + w;
      const int d  = l >> 1;
      const int kh = (l & 1) * 128;
      const int jd = jg * 32 + d;
      const float* wr = W + (size_t)jd * KDIM + kh;
      const float* yr = &sm.a.yt[w][kh];
      float p = 0.f;
#pragma unroll 8
      for (int k4 = 0; k4 < 32; ++k4) {
        f32x4 wv = *(const f32x4*)(wr + k4 * 4);
        f32x4 yv = *(const f32x4*)(yr + k4 * 4);
        p += wv.x * yv.x + wv.y * yv.y + wv.z * yv.z + wv.w * yv.w;
      }
      p += __shfl_xor(p, 1, 64);       // both lanes of pair hold s[jd]
      const float cs = cpart[((size_t)(b * 4 + 0)) * JCAP + jg] +
                       cpart[((size_t)(b * 4 + 1)) * JCAP + jg] +
                       cpart[((size_t)(b * 4 + 2)) * JCAP + jg] +
                       cpart[((size_t)(b * 4 + 3)) * JCAP + jg];
      const float wbv = Wb[jd];
      const float svv = p + cs * wbv;
      float sq = svv * svv;            // xor 2..32: one copy per d
      sq += __shfl_xor(sq, 2, 64);
      sq += __shfl_xor(sq, 4, 64);
      sq += __shfl_xor(sq, 8, 64);
      sq += __shfl_xor(sq, 16, 64);
      sq += __shfl_xor(sq, 32, 64);
      const float scale = (sq / (1.0f + sq)) / sqrtf(sq + 1e-8f);
      const float v = scale * svv;
      if (pass == 3) {
        if ((l & 1) == 0) outp[(size_t)b * OUTD + jd] = v;
      } else {
        if ((l & 1) == 0) sm.a.vls[w][d] = v;
        float up = v * wbv;
        up += __shfl_xor(up, 2, 64);
        up += __shfl_xor(up, 4, 64);
        up += __shfl_xor(up, 8, 64);
        up += __shfl_xor(up, 16, 64);
        up += __shfl_xor(up, 32, 64);
        if (l == 0) ubg[(size_t)b * JCAP + jg] = up;
      }
    }
    if (pass == 3) return;

    // ---- U: wave w owns jg; lanes span k (coalesced f32 W rows) -> LDS ----
    {
      const int jg = q * 16 + w;
      f32x4 acc = (f32x4){0.f, 0.f, 0.f, 0.f};
      const float* wr = W + (size_t)(jg * 32) * KDIM + l * 4;
#pragma unroll 4
      for (int dd = 0; dd < 32; ++dd) {
        const float vd = sm.a.vls[w][dd];
        f32x4 wv = *(const f32x4*)(wr + (size_t)dd * KDIM);
        acc.x += vd * wv.x; acc.y += vd * wv.y;
        acc.z += vd * wv.z; acc.w += vd * wv.w;
      }
      unsigned short h0 = f2bf(acc.x), h1 = f2bf(acc.y);
      unsigned short h2 = f2bf(acc.z), h3 = f2bf(acc.w);
      unsigned ph[2], pl[2];
      ph[0] = (unsigned)h0 | ((unsigned)h1 << 16);
      ph[1] = (unsigned)h2 | ((unsigned)h3 << 16);
      pl[0] = (unsigned)f2bf(acc.x - bf2f(h0)) | ((unsigned)f2bf(acc.y - bf2f(h1)) << 16);
      pl[1] = (unsigned)f2bf(acc.z - bf2f(h2)) | ((unsigned)f2bf(acc.w - bf2f(h3)) << 16);
      *(uint2*)&sm.a.ubf[0][w][l * 4] = *(uint2*)ph;
      *(uint2*)&sm.a.ubf[1][w][l * 4] = *(uint2*)pl;
    }
    __syncthreads();

    // ---- db MFMA: wave w -> i-tile w (rows 16w..16w+16), j = q*16+l15 ----
    {
      f32x4 acc = (f32x4){0.f, 0.f, 0.f, 0.f};
#pragma unroll
      for (int kk = 0; kk < 8; ++kk) {
        bf16x8 a  = xtf[kk];
        bf16x8 bh = *(const bf16x8*)&sm.a.ubf[0][l15][lhi * 8 + kk * 32];
        acc = __builtin_amdgcn_mfma_f32_16x16x32_bf16(a, bh, acc, 0, 0, 0);
        bf16x8 bl = *(const bf16x8*)&sm.a.ubf[1][l15][lhi * 8 + kk * 32];
        acc = __builtin_amdgcn_mfma_f32_16x16x32_bf16(a, bl, acc, 0, 0, 0);
      }
      const int ib = w * 16 + lhi * 4;
#pragma unroll
      for (int r = 0; r < 4; ++r)
        dbg[((size_t)((b * 4 + q) * ICAP) + ib + r) * 16 + l15] = acc[r];
    }
    group_barrier(gcnt + 2 * pass - 1);     // 1, 3

    // ---- B: softmax over j (q = i-quarter); logits in regs ----
    {
      const int i0b = q * 64;
      const int il = t >> 4, jc = (t & 15) * 4;
      const int qj = jc >> 4, c0 = jc & 15;
      const int ig = i0b + il;
      f32x4 db4 = *(const f32x4*)(dbg + ((size_t)((b * 4 + qj) * ICAP) + ig) * 16 + c0);
      f32x4 ub4 = *(const f32x4*)(ubg + (size_t)b * JCAP + jc);
      float bn[4];
      if (pass == 1) {
        f32x4 bo = *(const f32x4*)(btr + ((size_t)(b * ICAP + ig)) * JCAP + jc);
        bn[0] = bo.x; bn[1] = bo.y; bn[2] = bo.z; bn[3] = bo.w;
      } else {
#pragma unroll
        for (int e = 0; e < 4; ++e) bn[e] = blogreg[e];
      }
      const float dbv[4] = {db4.x, db4.y, db4.z, db4.w};
      const float ubv[4] = {ub4.x, ub4.y, ub4.z, ub4.w};
#pragma unroll
      for (int e = 0; e < 4; ++e) {
        bn[e] += dbv[e] + ubv[e];
        blogreg[e] = bn[e];
      }
      float mx = fmaxf(fmaxf(bn[0], bn[1]), fmaxf(bn[2], bn[3]));
      mx = fmaxf(mx, __shfl_xor(mx, 1, 64));
      mx = fmaxf(mx, __shfl_xor(mx, 2, 64));
      mx = fmaxf(mx, __shfl_xor(mx, 4, 64));
      mx = fmaxf(mx, __shfl_xor(mx, 8, 64));
      float e4[4], se = 0.f;
#pragma unroll
      for (int e = 0; e < 4; ++e) { e4[e] = __expf(bn[e] - mx); se += e4[e]; }
      se += __shfl_xor(se, 1, 64);
      se += __shfl_xor(se, 2, 64);
      se += __shfl_xor(se, 4, 64);
      se += __shfl_xor(se, 8, 64);
      const float inv = 1.0f / se;
      f32x4 cw; cw.x = e4[0] * inv; cw.y = e4[1] * inv;
      cw.z = e4[2] * inv; cw.w = e4[3] * inv;
      *(f32x4*)&sm.dbl[il][jc] = cw;
    }
    __syncthreads();
    {   // transpose-pack c -> cm + cpart
      const int i0b = q * 64;
      const int j2 = t >> 4, ic4 = (t & 15) * 4;
      float c0 = sm.dbl[ic4 + 0][j2], c1 = sm.dbl[ic4 + 1][j2];
      float c2 = sm.dbl[ic4 + 2][j2], c3 = sm.dbl[ic4 + 3][j2];
      unsigned pk[2];
      pk[0] = (unsigned)f2bf(c0) | ((unsigned)f2bf(c1) << 16);
      pk[1] = (unsigned)f2bf(c2) | ((unsigned)f2bf(c3) << 16);
      *(uint2*)(cm + ((size_t)(b * JCAP + j2)) * ICAP + i0b + ic4) = *(uint2*)pk;
      float cs = c0 + c1 + c2 + c3;
      cs += __shfl_xor(cs, 1, 64);
      cs += __shfl_xor(cs, 2, 64);
      cs += __shfl_xor(cs, 4, 64);
      cs += __shfl_xor(cs, 8, 64);
      if ((t & 15) == 0) cpart[((size_t)(b * 4 + q)) * JCAP + j2] = cs;
    }
    group_barrier(gcnt + 2 * pass);         // 2, 4
  }
}

// ---------------------------------------------------------------------------
extern "C" void kernel_launch(void* const* d_in, const int* in_sizes, int n_in,
                              void* d_out, int out_size, void* d_ws, size_t ws_size,
                              hipStream_t stream) {
  const float* x  = (const float*)d_in[0];
  const float* bi = (const float*)d_in[1];
  const float* W  = (const float*)d_in[2];
  const float* Wb = (const float*)d_in[3];
  float* out = (float*)d_out;

  char* ws = (char*)d_ws;
  const size_t MiB = 1024 * 1024;
  unsigned short* xT  = (unsigned short*)(ws + 0 * MiB);    // 8 MiB
  unsigned short* xKI = (unsigned short*)(ws + 8 * MiB);    // 8 MiB
  unsigned short* cm  = (unsigned short*)(ws + 16 * MiB);   // 2 MiB
  float* btr          = (float*)(ws + 18 * MiB);            // 4 MiB
  float* dbg          = (float*)(ws + 22 * MiB);            // 4 MiB
  float* cpart        = (float*)(ws + 26 * MiB);            // 64 KiB
  float* ubg          = (float*)(ws + 27 * MiB);            // 16 KiB
  int*   cnt          = (int*)(ws + 28 * MiB);              // 2 KiB

  hipMemsetAsync(cnt, 0, BS * 8 * sizeof(int), stream);
  mega<<<dim3(256), dim3(1024), 0, stream>>>(x, bi, W, Wb, xT, xKI, cm,
                                             dbg, btr, cpart, ubg, cnt, out);
}

// Round 8
// 207.199 us; speedup vs baseline: 1.1837x; 1.0652x over previous
//
#include <hip/hip_runtime.h>

// Sizes fixed by the problem.
#define BS    64
#define KDIM  256   // in_dim
#define ICAP  256   // I = 16*16
#define JCAP  64    // J out-caps
#define D2    32
#define OUTD  2048  // J*D2

typedef short bf16x8 __attribute__((ext_vector_type(8)));
typedef float f32x4  __attribute__((ext_vector_type(4)));

static __device__ __forceinline__ float bf2f(unsigned u16) {
  union { unsigned u; float f; } v; v.u = u16 << 16; return v.f;
}
static __device__ __forceinline__ unsigned short f2bf(float x) {
  union { float f; unsigned u; } v; v.f = x;
  unsigned r = v.u + 0x7fffu + ((v.u >> 16) & 1u);
  return (unsigned short)(r >> 16);
}

// group barrier: the 4 blocks of one b.
// KEY: spin with RELAXED loads (no per-poll L2 invalidate); exactly one
// ACQUIRE load after the target is reached. The fetch_add keeps RELEASE
// (single wbl2 flushing this block's writes). Counters are 128B apart.
static __device__ __forceinline__ void group_barrier(int* c) {
  __syncthreads();   // each wave's stores have drained (vmcnt0) before barrier
  if (threadIdx.x == 0) {
    __hip_atomic_fetch_add(c, 1, __ATOMIC_RELEASE, __HIP_MEMORY_SCOPE_AGENT);
    while (__hip_atomic_load(c, __ATOMIC_RELAXED, __HIP_MEMORY_SCOPE_AGENT) < 4)
      __builtin_amdgcn_s_sleep(2);
    (void)__hip_atomic_load(c, __ATOMIC_ACQUIRE, __HIP_MEMORY_SCOPE_AGENT);
  }
  __syncthreads();
}

// ---------------------------------------------------------------------------
// mega: 256 blocks = (b = bid&63, q = bid>>6), 1024 threads (16 waves).
//  P1 (q=k-quarter): x f32 -> xKI bf16 + xT bf16.
//  P2 (q=i-quarter): c0 softmax -> cm bf16 + cpart + btr.
//  [bar]
//  pass 1..2:
//   A (q=j-quarter): prefetch xT frags -> regs; Y MFMA -> yt LDS;
//     s scatter-stream (wave=j, lane=(d,khalf)) + squash -> v,ub;
//     U = v.W -> LDS bf16 hi/lo; db MFMA (xT regs x U LDS) -> dbg global.
//   [bar]
//   B (q=i-quarter): softmax(btr/regs + dbg + ub) -> cm + cpart.  [bar]
//  pass 3: Y; s -> squash -> out.
// ---------------------------------------------------------------------------
__global__ __launch_bounds__(1024) void mega(
    const float* __restrict__ x,            // [BS][KDIM][ICAP] f32
    const float* __restrict__ Binit,        // [BS][JCAP][ICAP] f32
    const float* __restrict__ W,            // [OUTD][KDIM] f32
    const float* __restrict__ Wb,           // [OUTD] f32
    unsigned short* __restrict__ xT,        // [BS][ICAP][KDIM] bf16
    unsigned short* __restrict__ xKI,       // [BS][KDIM][ICAP] bf16
    unsigned short* __restrict__ cm,        // [BS][JCAP][ICAP] bf16
    float* __restrict__ dbg,                // [BS][4][ICAP][16] f32
    float* __restrict__ btr,                // [BS][ICAP][JCAP] f32
    float* __restrict__ cpart,              // [BS][4][JCAP] f32
    float* __restrict__ ubg,                // [BS][JCAP] f32
    int* __restrict__ cnt,                  // [BS][5][32] barrier counters
    float* __restrict__ outp)               // [BS][OUTD] f32
{
  __shared__ union {
    float xs[64][260];                                           // P1
    struct { float Bs[64][68]; float mx[64]; float inv[64]; } p2;
    struct {
      float yt[16][260];                   // Y^T [j-local][k] f32
      float vls[16][33];                   // v   [j-local][d]
      unsigned short ubf[2][16][264];      // U hi/lo bf16 [j-local][k]
    } a;
    float dbl[64][65];                                           // B softmax
  } sm;

  const int t   = threadIdx.x;        // 0..1023
  const int u   = blockIdx.x;         // 0..255
  const int b   = u & 63;
  const int q   = u >> 6;
  const int w   = t >> 6;             // wave 0..15
  const int l   = t & 63;
  const int l15 = l & 15;
  const int lhi = l >> 4;             // 0..3
  int* gcnt = cnt + b * 5 * 32;       // one 128B line per event

  // ---------------- P1: x prep (q = k-quarter) ----------------
  {
    const int k0  = q * 64;
    const int r   = t >> 4;             // k-row 0..63
    const int c16 = (t & 15) * 16;      // i-chunk
    const float* src = x + ((size_t)(b * KDIM + k0 + r)) * ICAP + c16;
    f32x4 vv[4];
#pragma unroll
    for (int e = 0; e < 4; ++e) vv[e] = *(const f32x4*)(src + e * 4);
    {   // xKI straight cast
      const float* fv = (const float*)vv;
      unsigned pk[8];
#pragma unroll
      for (int h = 0; h < 8; ++h)
        pk[h] = (unsigned)f2bf(fv[2 * h]) | ((unsigned)f2bf(fv[2 * h + 1]) << 16);
      unsigned short* dst = xKI + ((size_t)(b * KDIM + k0 + r)) * ICAP + c16;
      *(uint4*)(dst)     = *(uint4*)&pk[0];
      *(uint4*)(dst + 8) = *(uint4*)&pk[4];
    }
#pragma unroll
    for (int e = 0; e < 4; ++e) *(f32x4*)&sm.xs[r][c16 + e * 4] = vv[e];
  }
  __syncthreads();
  {   // xT transpose out of LDS
    const int k0 = q * 64;
    const int i  = t >> 2;              // 0..255
    const int kq = (t & 3) * 16;
    unsigned pk[8];
#pragma unroll
    for (int h = 0; h < 8; ++h)
      pk[h] = (unsigned)f2bf(sm.xs[kq + 2 * h][i]) |
              ((unsigned)f2bf(sm.xs[kq + 2 * h + 1][i]) << 16);
    unsigned short* dst = xT + ((size_t)(b * ICAP + i)) * KDIM + k0 + kq;
    *(uint4*)(dst)     = *(uint4*)&pk[0];
    *(uint4*)(dst + 8) = *(uint4*)&pk[4];
  }
  __syncthreads();

  // ---------------- P2: Binit softmax (q = i-quarter) ----------------
  {
    const int i0 = q * 64;
    {
      const int j = t >> 4, c4 = (t & 15) * 4;
      *(f32x4*)&sm.p2.Bs[j][c4] =
          *(const f32x4*)(Binit + ((size_t)(b * JCAP + j)) * ICAP + i0 + c4);
    }
    __syncthreads();
    if (t < 64) {
      float m = -3.0e38f;
      for (int j = 0; j < 64; ++j) m = fmaxf(m, sm.p2.Bs[j][t]);
      float se = 0.f;
      for (int j = 0; j < 64; ++j) se += __expf(sm.p2.Bs[j][t] - m);
      sm.p2.mx[t] = m; sm.p2.inv[t] = 1.0f / se;
    }
    __syncthreads();
    {   // cm + cpart
      const int j = t >> 4, i4 = (t & 15) * 4;
      float cv[4];
#pragma unroll
      for (int e = 0; e < 4; ++e)
        cv[e] = __expf(sm.p2.Bs[j][i4 + e] - sm.p2.mx[i4 + e]) * sm.p2.inv[i4 + e];
      unsigned pk[2];
      pk[0] = (unsigned)f2bf(cv[0]) | ((unsigned)f2bf(cv[1]) << 16);
      pk[1] = (unsigned)f2bf(cv[2]) | ((unsigned)f2bf(cv[3]) << 16);
      *(uint2*)(cm + ((size_t)(b * JCAP + j)) * ICAP + i0 + i4) = *(uint2*)pk;
      float cs = cv[0] + cv[1] + cv[2] + cv[3];
      cs += __shfl_xor(cs, 1, 64);
      cs += __shfl_xor(cs, 2, 64);
      cs += __shfl_xor(cs, 4, 64);
      cs += __shfl_xor(cs, 8, 64);
      if ((t & 15) == 0) cpart[((size_t)(b * 4 + q)) * JCAP + j] = cs;
    }
    {   // btr: transposed logits for pass-1 coalesced read
      const int il = t >> 4, j4 = (t & 15) * 4;
      f32x4 o;
      o.x = sm.p2.Bs[j4 + 0][il]; o.y = sm.p2.Bs[j4 + 1][il];
      o.z = sm.p2.Bs[j4 + 2][il]; o.w = sm.p2.Bs[j4 + 3][il];
      *(f32x4*)(btr + ((size_t)(b * ICAP + i0 + il)) * JCAP + j4) = o;
    }
  }
  group_barrier(gcnt + 0 * 32);

  // ---------------- routing passes ----------------
  float blogreg[4];

  for (int pass = 1; pass <= 3; ++pass) {
    // ---- prefetch xT A-fragments for db (pass-invariant addresses) ----
    bf16x8 xtf[8];
    if (pass != 3) {
      const unsigned short* Ar =
          xT + ((size_t)(b * ICAP + w * 16 + l15)) * KDIM + lhi * 8;
#pragma unroll
      for (int kk = 0; kk < 8; ++kk) xtf[kk] = *(const bf16x8*)(Ar + kk * 32);
    }

    // ---- Y MFMA: yt[j-local][k] = sum_i xKI[k][i]*cm[q*16+jl][i] ----
    {
      f32x4 acc = (f32x4){0.f, 0.f, 0.f, 0.f};
      const unsigned short* Ar =
          xKI + ((size_t)(b * KDIM + w * 16 + l15)) * ICAP + lhi * 8;
      const unsigned short* Br =
          cm + ((size_t)(b * JCAP + q * 16 + l15)) * ICAP + lhi * 8;
#pragma unroll
      for (int kk = 0; kk < 8; ++kk) {
        bf16x8 a  = *(const bf16x8*)(Ar + kk * 32);
        bf16x8 bb = *(const bf16x8*)(Br + kk * 32);
        acc = __builtin_amdgcn_mfma_f32_16x16x32_bf16(a, bb, acc, 0, 0, 0);
      }
      *(f32x4*)&sm.a.yt[l15][w * 16 + lhi * 4] = acc;
    }
    __syncthreads();

    // ---- s: wave w owns j = q*16+w; lane = (d = l>>1, khalf = l&1) ----
    {
      const int jg = q * 16 + w;
      const int d  = l >> 1;
      const int kh = (l & 1) * 128;
      const int jd = jg * 32 + d;
      const float* wr = W + (size_t)jd * KDIM + kh;
      const float* yr = &sm.a.yt[w][kh];
      float p = 0.f;
#pragma unroll 8
      for (int k4 = 0; k4 < 32; ++k4) {
        f32x4 wv = *(const f32x4*)(wr + k4 * 4);
        f32x4 yv = *(const f32x4*)(yr + k4 * 4);
        p += wv.x * yv.x + wv.y * yv.y + wv.z * yv.z + wv.w * yv.w;
      }
      p += __shfl_xor(p, 1, 64);       // both lanes of pair hold s[jd]
      const float cs = cpart[((size_t)(b * 4 + 0)) * JCAP + jg] +
                       cpart[((size_t)(b * 4 + 1)) * JCAP + jg] +
                       cpart[((size_t)(b * 4 + 2)) * JCAP + jg] +
                       cpart[((size_t)(b * 4 + 3)) * JCAP + jg];
      const float wbv = Wb[jd];
      const float svv = p + cs * wbv;
      float sq = svv * svv;            // xor 2..32: one copy per d
      sq += __shfl_xor(sq, 2, 64);
      sq += __shfl_xor(sq, 4, 64);
      sq += __shfl_xor(sq, 8, 64);
      sq += __shfl_xor(sq, 16, 64);
      sq += __shfl_xor(sq, 32, 64);
      const float scale = (sq / (1.0f + sq)) / sqrtf(sq + 1e-8f);
      const float v = scale * svv;
      if (pass == 3) {
        if ((l & 1) == 0) outp[(size_t)b * OUTD + jd] = v;
      } else {
        if ((l & 1) == 0) sm.a.vls[w][d] = v;
        float up = v * wbv;
        up += __shfl_xor(up, 2, 64);
        up += __shfl_xor(up, 4, 64);
        up += __shfl_xor(up, 8, 64);
        up += __shfl_xor(up, 16, 64);
        up += __shfl_xor(up, 32, 64);
        if (l == 0) ubg[(size_t)b * JCAP + jg] = up;
      }
    }
    if (pass == 3) return;

    // ---- U: wave w owns jg; lanes span k (coalesced f32 W rows) -> LDS ----
    {
      const int jg = q * 16 + w;
      f32x4 acc = (f32x4){0.f, 0.f, 0.f, 0.f};
      const float* wr = W + (size_t)(jg * 32) * KDIM + l * 4;
#pragma unroll 4
      for (int dd = 0; dd < 32; ++dd) {
        const float vd = sm.a.vls[w][dd];
        f32x4 wv = *(const f32x4*)(wr + (size_t)dd * KDIM);
        acc.x += vd * wv.x; acc.y += vd * wv.y;
        acc.z += vd * wv.z; acc.w += vd * wv.w;
      }
      unsigned short h0 = f2bf(acc.x), h1 = f2bf(acc.y);
      unsigned short h2 = f2bf(acc.z), h3 = f2bf(acc.w);
      unsigned ph[2], pl[2];
      ph[0] = (unsigned)h0 | ((unsigned)h1 << 16);
      ph[1] = (unsigned)h2 | ((unsigned)h3 << 16);
      pl[0] = (unsigned)f2bf(acc.x - bf2f(h0)) | ((unsigned)f2bf(acc.y - bf2f(h1)) << 16);
      pl[1] = (unsigned)f2bf(acc.z - bf2f(h2)) | ((unsigned)f2bf(acc.w - bf2f(h3)) << 16);
      *(uint2*)&sm.a.ubf[0][w][l * 4] = *(uint2*)ph;
      *(uint2*)&sm.a.ubf[1][w][l * 4] = *(uint2*)pl;
    }
    __syncthreads();

    // ---- db MFMA: wave w -> i-tile w (rows 16w..16w+16), j = q*16+l15 ----
    {
      f32x4 acc = (f32x4){0.f, 0.f, 0.f, 0.f};
#pragma unroll
      for (int kk = 0; kk < 8; ++kk) {
        bf16x8 a  = xtf[kk];
        bf16x8 bh = *(const bf16x8*)&sm.a.ubf[0][l15][lhi * 8 + kk * 32];
        acc = __builtin_amdgcn_mfma_f32_16x16x32_bf16(a, bh, acc, 0, 0, 0);
        bf16x8 bl = *(const bf16x8*)&sm.a.ubf[1][l15][lhi * 8 + kk * 32];
        acc = __builtin_amdgcn_mfma_f32_16x16x32_bf16(a, bl, acc, 0, 0, 0);
      }
      const int ib = w * 16 + lhi * 4;
#pragma unroll
      for (int r = 0; r < 4; ++r)
        dbg[((size_t)((b * 4 + q) * ICAP) + ib + r) * 16 + l15] = acc[r];
    }
    group_barrier(gcnt + (2 * pass - 1) * 32);     // events 1, 3

    // ---- B: softmax over j (q = i-quarter); logits in regs ----
    {
      const int i0b = q * 64;
      const int il = t >> 4, jc = (t & 15) * 4;
      const int qj = jc >> 4, c0 = jc & 15;
      const int ig = i0b + il;
      f32x4 db4 = *(const f32x4*)(dbg + ((size_t)((b * 4 + qj) * ICAP) + ig) * 16 + c0);
      f32x4 ub4 = *(const f32x4*)(ubg + (size_t)b * JCAP + jc);
      float bn[4];
      if (pass == 1) {
        f32x4 bo = *(const f32x4*)(btr + ((size_t)(b * ICAP + ig)) * JCAP + jc);
        bn[0] = bo.x; bn[1] = bo.y; bn[2] = bo.z; bn[3] = bo.w;
      } else {
#pragma unroll
        for (int e = 0; e < 4; ++e) bn[e] = blogreg[e];
      }
      const float dbv[4] = {db4.x, db4.y, db4.z, db4.w};
      const float ubv[4] = {ub4.x, ub4.y, ub4.z, ub4.w};
#pragma unroll
      for (int e = 0; e < 4; ++e) {
        bn[e] += dbv[e] + ubv[e];
        blogreg[e] = bn[e];
      }
      float mx = fmaxf(fmaxf(bn[0], bn[1]), fmaxf(bn[2], bn[3]));
      mx = fmaxf(mx, __shfl_xor(mx, 1, 64));
      mx = fmaxf(mx, __shfl_xor(mx, 2, 64));
      mx = fmaxf(mx, __shfl_xor(mx, 4, 64));
      mx = fmaxf(mx, __shfl_xor(mx, 8, 64));
      float e4[4], se = 0.f;
#pragma unroll
      for (int e = 0; e < 4; ++e) { e4[e] = __expf(bn[e] - mx); se += e4[e]; }
      se += __shfl_xor(se, 1, 64);
      se += __shfl_xor(se, 2, 64);
      se += __shfl_xor(se, 4, 64);
      se += __shfl_xor(se, 8, 64);
      const float inv = 1.0f / se;
      f32x4 cw; cw.x = e4[0] * inv; cw.y = e4[1] * inv;
      cw.z = e4[2] * inv; cw.w = e4[3] * inv;
      *(f32x4*)&sm.dbl[il][jc] = cw;
    }
    __syncthreads();
    {   // transpose-pack c -> cm + cpart
      const int i0b = q * 64;
      const int j2 = t >> 4, ic4 = (t & 15) * 4;
      float c0 = sm.dbl[ic4 + 0][j2], c1 = sm.dbl[ic4 + 1][j2];
      float c2 = sm.dbl[ic4 + 2][j2], c3 = sm.dbl[ic4 + 3][j2];
      unsigned pk[2];
      pk[0] = (unsigned)f2bf(c0) | ((unsigned)f2bf(c1) << 16);
      pk[1] = (unsigned)f2bf(c2) | ((unsigned)f2bf(c3) << 16);
      *(uint2*)(cm + ((size_t)(b * JCAP + j2)) * ICAP + i0b + ic4) = *(uint2*)pk;
      float cs = c0 + c1 + c2 + c3;
      cs += __shfl_xor(cs, 1, 64);
      cs += __shfl_xor(cs, 2, 64);
      cs += __shfl_xor(cs, 4, 64);
      cs += __shfl_xor(cs, 8, 64);
      if ((t & 15) == 0) cpart[((size_t)(b * 4 + q)) * JCAP + j2] = cs;
    }
    group_barrier(gcnt + (2 * pass) * 32);         // events 2, 4
  }
}

// ---------------------------------------------------------------------------
extern "C" void kernel_launch(void* const* d_in, const int* in_sizes, int n_in,
                              void* d_out, int out_size, void* d_ws, size_t ws_size,
                              hipStream_t stream) {
  const float* x  = (const float*)d_in[0];
  const float* bi = (const float*)d_in[1];
  const float* W  = (const float*)d_in[2];
  const float* Wb = (const float*)d_in[3];
  float* out = (float*)d_out;

  char* ws = (char*)d_ws;
  const size_t MiB = 1024 * 1024;
  unsigned short* xT  = (unsigned short*)(ws + 0 * MiB);    // 8 MiB
  unsigned short* xKI = (unsigned short*)(ws + 8 * MiB);    // 8 MiB
  unsigned short* cm  = (unsigned short*)(ws + 16 * MiB);   // 2 MiB
  float* btr          = (float*)(ws + 18 * MiB);            // 4 MiB
  float* dbg          = (float*)(ws + 22 * MiB);            // 4 MiB
  float* cpart        = (float*)(ws + 26 * MiB);            // 64 KiB
  float* ubg          = (float*)(ws + 27 * MiB);            // 16 KiB
  int*   cnt          = (int*)(ws + 28 * MiB);              // 40 KiB

  hipMemsetAsync(cnt, 0, BS * 5 * 32 * sizeof(int), stream);
  mega<<<dim3(256), dim3(1024), 0, stream>>>(x, bi, W, Wb, xT, xKI, cm,
                                             dbg, btr, cpart, ubg, cnt, out);
}